// Round 15
// baseline (5355.174 us; speedup 1.0000x reference)
//
#include <hip/hip_runtime.h>
#include <hip/hip_bf16.h>

#define VOCAB 32000
#define EMBED 512
#define ENCD  512
#define HID   1024
#define ATTN  128
#define SRC   1024
#define TGT   512
#define NB    64          // recurrence blocks (proven sweet spot)
#define NBW   127         // 64 recurrence + 63 logits-worker blocks
#define NT    512         // threads per block
#define CHUNK 64          // steps per launch (r13-proven)

typedef __hip_bfloat16 bf16;
typedef _Float16 f16;
typedef __attribute__((ext_vector_type(2))) _Float16 f16x2;
typedef __attribute__((ext_vector_type(8))) _Float16 f16x8;
typedef __attribute__((ext_vector_type(8))) short bf16x8v;
typedef __attribute__((ext_vector_type(4))) float f32x4;

// ---- workspace layout (float offsets), ~23.9 MB total (r13 layout) ----
#define OFF_TP    0           // u32 [1024][128] {T, v*T} f16 pairs
#define OFF_G     131072      // f16 [512][4096] gate bases, prow-permuted
#define OFF_HH    1179648     // f32 [513][1024] h history
#define OFF_CC    1704960     // f32 [1024] c state
#define OFF_WAHPB 1705984     // f32 [2][64][128] wahp partials dbuf (atomic)
#define OFF_PB    1722368     // f32 [2][1024] unnorm p dbuf        (atomic)
#define OFF_HBUF  1724416     // u32 [2][512] h packed f16x2 dbuf   (atomic)
#define OFF_CTR   1725440     // u32 [3] counters (+pad)            (atomic)
#define OFF_WAHT  1725504     // f16 [64][128][16] Wa_h block-sliced
#define OFF_WHH   1791040     // f16 [4096][1024] W_hh, prow-permuted
#define OFF_VT    3888192     // f16 [4096][1024] V[prow][s]

__device__ __forceinline__ float sigm(float x){ return 1.f/(1.f+__expf(-x)); }
__device__ __forceinline__ float tanh_f(float x){
  float ax = fabsf(x);
  float e = __expf(-2.f*ax);
  float r = (1.f - e) / (1.f + e);
  return copysignf(r, x);
}
__device__ __forceinline__ short f2bs(float x){
  union { bf16 h; short s; } u; u.h = __float2bfloat16(x); return u.s;
}
__device__ __forceinline__ bf16x8v cvt8(const float* p){
  float4 a = *reinterpret_cast<const float4*>(p);
  float4 b = *reinterpret_cast<const float4*>(p+4);
  bf16x8v r;
  r[0]=f2bs(a.x); r[1]=f2bs(a.y); r[2]=f2bs(a.z); r[3]=f2bs(a.w);
  r[4]=f2bs(b.x); r[5]=f2bs(b.y); r[6]=f2bs(b.z); r[7]=f2bs(b.w);
  return r;
}
__device__ __forceinline__ float aldf(const float* p){
  return __hip_atomic_load(p, __ATOMIC_RELAXED, __HIP_MEMORY_SCOPE_AGENT);
}
__device__ __forceinline__ void astf(float* p, float v){
  __hip_atomic_store(p, v, __ATOMIC_RELAXED, __HIP_MEMORY_SCOPE_AGENT);
}
__device__ __forceinline__ unsigned aldu(const unsigned* p){
  return __hip_atomic_load(p, __ATOMIC_RELAXED, __HIP_MEMORY_SCOPE_AGENT);
}
__device__ __forceinline__ void astu(unsigned* p, unsigned v){
  __hip_atomic_store(p, v, __ATOMIC_RELAXED, __HIP_MEMORY_SCOPE_AGENT);
}

// ---- one-time: TP[s][a] = {T, v_a*T}, T = clamp(tanh(enc_proj)) (grid 64x128) ----
__global__ void k_encTP(const float* __restrict__ enc, const float* __restrict__ Wa_enc,
                        const float* __restrict__ v_a, unsigned* __restrict__ TP){
  __shared__ float eL[16][ENCD];
  int s0 = blockIdx.x*16, tid = threadIdx.x;
  #pragma unroll
  for (int i=0;i<16;i++){
    int li = tid + i*128;
    int t = li>>7, k4 = li&127;
    *reinterpret_cast<float4*>(&eL[t][k4*4]) =
      *reinterpret_cast<const float4*>(enc + (size_t)(s0+t)*ENCD + k4*4);
  }
  __syncthreads();
  const float* w = Wa_enc + (size_t)tid*ENCD;
  float va = v_a[tid];
  float acc[16];
  #pragma unroll
  for (int t=0;t<16;t++) acc[t]=0.f;
  for (int k4=0;k4<128;k4++){
    float4 wv = *reinterpret_cast<const float4*>(w + k4*4);
    #pragma unroll
    for (int t=0;t<16;t++){
      float4 e4 = *reinterpret_cast<const float4*>(&eL[t][k4*4]);
      acc[t] += wv.x*e4.x + wv.y*e4.y + wv.z*e4.z + wv.w*e4.w;
    }
  }
  #pragma unroll
  for (int t=0;t<16;t++){
    float th = tanh_f(acc[t]);
    th = fminf(0.9995f, fmaxf(-0.9995f, th));
    union { f16x2 h; unsigned u; } cv;
    cv.h = (f16x2){ (f16)th, (f16)(va*th) };
    TP[(size_t)(s0+t)*ATTN + tid] = cv.u;
  }
}

// ---- one-time: Gp[t][prow] f16, prow = (j>>4)*64 + g*16 + (j&15) ----
__global__ void k_gbase(const int* __restrict__ sos, const int* __restrict__ tgt,
                        const float* __restrict__ embt, const float* __restrict__ W_ih,
                        const float* __restrict__ b_ih, const float* __restrict__ b_hh,
                        f16* __restrict__ Gp){
  __shared__ float eL[16][EMBED];
  int tid = threadIdx.x;
  int t0 = blockIdx.y*16;
  #pragma unroll
  for (int i=0;i<8;i++){
    int li = tid + i*256;
    int t = li>>7, k4 = li&127;
    int tg = t0 + t;
    int tok = (tg==0) ? sos[0] : tgt[tg-1];
    *reinterpret_cast<float4*>(&eL[t][k4*4]) =
      *reinterpret_cast<const float4*>(embt + (size_t)tok*EMBED + k4*4);
  }
  __syncthreads();
  int r = blockIdx.x*256 + tid;
  int g = r>>10, j = r&1023;
  int prow = (j>>4)*64 + g*16 + (j&15);
  const float* w = W_ih + (size_t)r*(EMBED+ENCD);
  float base = b_ih[r] + b_hh[r];
  float acc[16];
  #pragma unroll
  for (int t=0;t<16;t++) acc[t]=0.f;
  for (int k4=0;k4<128;k4++){
    float4 wv = *reinterpret_cast<const float4*>(w + k4*4);
    #pragma unroll
    for (int t=0;t<16;t++){
      float4 e4 = *reinterpret_cast<const float4*>(&eL[t][k4*4]);
      acc[t] += wv.x*e4.x + wv.y*e4.y + wv.z*e4.z + wv.w*e4.w;
    }
  }
  #pragma unroll
  for (int t=0;t<16;t++) Gp[(size_t)(t0+t)*4096 + prow] = (f16)(acc[t] + base);
}

// ---- one-time: W_hh -> f16 permuted rows ----
__global__ void k_cvt_whh(const float* __restrict__ W, f16* __restrict__ out){
  int r = blockIdx.x;
  int g = r >> 10, j = r & 1023;
  int prow = (j>>4)*64 + g*16 + (j&15);
  int k0 = threadIdx.x*8;
  float4 a = *reinterpret_cast<const float4*>(W + (size_t)r*HID + k0);
  float4 c = *reinterpret_cast<const float4*>(W + (size_t)r*HID + k0 + 4);
  f16x8 v = { (f16)a.x,(f16)a.y,(f16)a.z,(f16)a.w,(f16)c.x,(f16)c.y,(f16)c.z,(f16)c.w };
  *reinterpret_cast<f16x8*>(out + (size_t)prow*HID + k0) = v;
}
// ---- one-time: WahT[b][a][j] = Wa_h[a][b*16+j] f16 (grid 64 x 128) ----
__global__ void k_cvt_wahT(const float* __restrict__ W, f16* __restrict__ out){
  int b = blockIdx.x, a = threadIdx.x;
  const float* src = W + (size_t)a*HID + b*16;
  float4 v0 = *reinterpret_cast<const float4*>(src);
  float4 v1 = *reinterpret_cast<const float4*>(src+4);
  float4 v2 = *reinterpret_cast<const float4*>(src+8);
  float4 v3 = *reinterpret_cast<const float4*>(src+12);
  f16* dst = out + ((size_t)b*128 + a)*16;
  f16x8 w0 = { (f16)v0.x,(f16)v0.y,(f16)v0.z,(f16)v0.w,(f16)v1.x,(f16)v1.y,(f16)v1.z,(f16)v1.w };
  f16x8 w1 = { (f16)v2.x,(f16)v2.y,(f16)v2.z,(f16)v2.w,(f16)v3.x,(f16)v3.y,(f16)v3.z,(f16)v3.w };
  *reinterpret_cast<f16x8*>(dst)   = w0;
  *reinterpret_cast<f16x8*>(dst+8) = w1;
}

// ---- one-time: Vt[prow][s] = Wihc[prow]·enc[s] via bf16 MFMA (grid 8 x 32) ----
__global__ __launch_bounds__(256) void k_gemmV(const float* __restrict__ W_ih,
                                               const float* __restrict__ enc,
                                               f16* __restrict__ Vt){
  int bn = blockIdx.x, bm = blockIdx.y;
  int tid = threadIdx.x;
  int wid = tid>>6, lane = tid&63;
  int wr = wid>>1, wc = wid&1;
  int rowf = lane&15, kg = lane>>4;
  const int m_base = bm*128 + wr*64;
  const int n_base = bn*128 + wc*64;
  const float* Ap[4];
  #pragma unroll
  for (int mt=0;mt<4;mt++){
    int prow = m_base + mt*16 + rowf;
    int bb = prow>>6, g = (prow>>4)&3, jl = prow&15;   // inverse perm
    int r = g*HID + bb*16 + jl;
    Ap[mt] = W_ih + (size_t)r*(EMBED+ENCD) + EMBED + kg*8;
  }
  const float* Bp = enc + (size_t)(n_base + rowf)*ENCD + kg*8;
  f32x4 acc[4][4];
  #pragma unroll
  for (int i=0;i<4;i++)
    #pragma unroll
    for (int jv=0;jv<4;jv++) acc[i][jv] = (f32x4){0.f,0.f,0.f,0.f};
  for (int kk=0; kk<ENCD; kk+=32){
    bf16x8v av[4], bv[4];
    #pragma unroll
    for (int mt=0;mt<4;mt++) av[mt] = cvt8(Ap[mt] + kk);
    #pragma unroll
    for (int nt=0;nt<4;nt++) bv[nt] = cvt8(Bp + (size_t)nt*16*ENCD + kk);
    #pragma unroll
    for (int mt=0;mt<4;mt++)
      #pragma unroll
      for (int nt=0;nt<4;nt++)
        acc[mt][nt] = __builtin_amdgcn_mfma_f32_16x16x32_bf16(av[mt], bv[nt], acc[mt][nt], 0,0,0);
  }
  #pragma unroll
  for (int mt=0;mt<4;mt++){
    #pragma unroll
    for (int nt=0;nt<4;nt++){
      int n = n_base + nt*16 + rowf;
      #pragma unroll
      for (int i=0;i<4;i++){
        int m = m_base + mt*16 + kg*4 + i;
        Vt[(size_t)m*SRC + n] = (f16)acc[mt][nt][i];
      }
    }
  }
}

// ---- one-time: Hh[0]=h0, Cc=c0, hbuf[0], wahp[0], ctr=0 (grid 64 x 128) ----
__global__ void k_prep0(const float* __restrict__ h0, const float* __restrict__ c0,
                        const float* __restrict__ Wa_h,
                        float* __restrict__ Hh, float* __restrict__ Cc,
                        unsigned* __restrict__ hbuf, float* __restrict__ wahpb,
                        unsigned* __restrict__ ctr){
  int b = blockIdx.x, tid = threadIdx.x;
  if (b < 8){ Hh[b*128+tid] = h0[b*128+tid]; Cc[b*128+tid] = c0[b*128+tid]; }
  if (b < 4){
    int i = b*128 + tid;
    union { f16x2 h; unsigned u; } cv;
    cv.h = (f16x2){ (f16)h0[2*i], (f16)h0[2*i+1] };
    hbuf[i] = cv.u;
  }
  if (b == 0 && tid < 3) ctr[tid] = 0u;
  __shared__ float hl[16];
  if (tid < 16) hl[tid] = h0[b*16 + tid];
  __syncthreads();
  const float* wr = Wa_h + (size_t)tid*HID + b*16;
  float acc = 0.f;
  #pragma unroll
  for (int i4=0;i4<4;i4++){
    float4 w4 = *reinterpret_cast<const float4*>(wr + i4*4);
    acc += w4.x*hl[i4*4] + w4.y*hl[i4*4+1] + w4.z*hl[i4*4+2] + w4.w*hl[i4*4+3];
  }
  wahpb[b*128 + tid] = acc;   // parity 0
}

// ---- CHUNK steps per launch. Blocks 0..63: r13 recurrence (2 counter syncs).
//      Blocks 64..126: logits workers for the PREVIOUS chunk's t-stripe. ----
__global__ __launch_bounds__(NT) void k_multi(int t0,
    const unsigned* __restrict__ TP, const f16* __restrict__ WahT,
    const f16* __restrict__ Whh_h, const f16* __restrict__ Vt,
    const f16* __restrict__ Gp, const float* __restrict__ v_a,
    float* __restrict__ Hh, float* __restrict__ Cc,
    float* __restrict__ wahpb, float* __restrict__ pbuf,
    unsigned* __restrict__ hbuf, unsigned* __restrict__ ctr,
    float* __restrict__ Pout,
    const float* __restrict__ Wout, const float* __restrict__ bout,
    float* __restrict__ Clog)
{
  const int b = blockIdx.x, tid = threadIdx.x;
  __shared__ f16x8 hs8[128];       // h_t packed, swizzled [(c&15)*8+(c>>4)]
  __shared__ f16x8 ps8[128];       // normalized p packed, same swizzle
  __shared__ float2 vwp[128];      // {tanh(wah), v*tanh(wah)}
  __shared__ float vas[128];
  __shared__ float gacc[64];
  __shared__ float g2[64];
  __shared__ float pown[16];
  __shared__ float hnl[16];
  __shared__ f16x2 hnl2[8];
  __shared__ float wpart[8];
  __shared__ float invs;
  __shared__ float cst[16];
  __shared__ f16x2 hL[16][512];    // worker: 16 h-rows as f16 pairs (32 KB)

  if (b < NB){
    // ================= recurrence path (r13, byte-identical) =================
    const int l8 = tid >> 3, q8 = tid & 7;   // matvec: 64 rows x 8 lanes

    if (tid < 16)  cst[tid] = Cc[b*16 + tid];
    if (tid < 128) vas[tid] = v_a[tid];

    for (int k = 0; k < CHUNK; ++k){
      const int t = t0 + k;
      const unsigned base = 64u*(unsigned)t;
      // ---- S0: wait h+wahp ready (single sync); load h; reduce wahp ----
      if (tid == 0){
        while (aldu(&ctr[2]) < base) __builtin_amdgcn_s_sleep(1);
      }
      __syncthreads();
      if (tid < 128){
        const unsigned* hp = hbuf + (t&1)*512 + tid*4;
        union { unsigned u[4]; f16x8 v; } cv;
        cv.u[0]=aldu(hp); cv.u[1]=aldu(hp+1); cv.u[2]=aldu(hp+2); cv.u[3]=aldu(hp+3);
        hs8[(tid&15)*8 + (tid>>4)] = cv.v;
      }
      {
        int a = tid >> 2, lane4 = tid & 3;
        const float* wp = wahpb + (t&1)*8192 + lane4*128 + a;
        float acc = 0.f;
        #pragma unroll
        for (int m = 0; m < 16; ++m) acc += aldf(wp + m*512);
        acc += __shfl_xor(acc,1); acc += __shfl_xor(acc,2);
        if (lane4 == 0){
          float tw = tanh_f(acc);
          vwp[a] = make_float2(tw, vas[a]*tw);
        }
      }
      __syncthreads();
      // ---- S1: scores for own 16 s-rows; publish p ----
      {
        int row = tid >> 5, l5 = tid & 31;
        const f16x8* tp8 = (const f16x8*)((const f16*)TP + ((size_t)(b*16+row)*ATTN + l5*4)*2);
        f16x8 tv = tp8[0];
        float sc = 0.f;
        #pragma unroll
        for (int u = 0; u < 4; ++u){
          float T  = (float)tv[2*u];
          float vT = (float)tv[2*u+1];
          float2 vw = vwp[l5*4 + u];
          float num = vT + vw.y;
          float den = fmaf(T, vw.x, 1.f);
          sc = fmaf(num, __builtin_amdgcn_rcpf(den), sc);
        }
        sc += __shfl_xor(sc,1); sc += __shfl_xor(sc,2); sc += __shfl_xor(sc,4);
        sc += __shfl_xor(sc,8); sc += __shfl_xor(sc,16);
        if (l5 == 0){
          float pv = __expf(sc);
          pown[row] = pv;
          astf(&pbuf[(t&1)*1024 + b*16 + row], pv);
        }
      }
      __syncthreads();                                  // drain p stores
      if (tid == 0)
        __hip_atomic_fetch_add(&ctr[1], 1u, __ATOMIC_RELAXED, __HIP_MEMORY_SCOPE_AGENT);
      // ---- S2: full gacc = Whh·h (hides p round-trip) ----
      {
        const f16x8* wr = (const f16x8*)(Whh_h + (size_t)(b*64 + l8)*HID + q8*128);
        float ga = 0.f;
        #pragma unroll
        for (int i = 0; i < 16; ++i){
          f16x8 wv = wr[i];
          f16x8 hv = hs8[i*8 + q8];
          const f16x2* wp = (const f16x2*)&wv;
          const f16x2* hp = (const f16x2*)&hv;
          ga = __builtin_amdgcn_fdot2(wp[0], hp[0], ga, false);
          ga = __builtin_amdgcn_fdot2(wp[1], hp[1], ga, false);
          ga = __builtin_amdgcn_fdot2(wp[2], hp[2], ga, false);
          ga = __builtin_amdgcn_fdot2(wp[3], hp[3], ga, false);
        }
        ga += __shfl_xor(ga,1); ga += __shfl_xor(ga,2); ga += __shfl_xor(ga,4);
        if (q8 == 0) gacc[l8] = ga;
      }
      // ---- S3: wait p; normalize + pack ----
      if (tid == 0){
        while (aldu(&ctr[1]) < base + 64u) __builtin_amdgcn_s_sleep(1);
      }
      __syncthreads();
      {
        float p0 = aldf(&pbuf[(t&1)*1024 + 2*tid]);
        float p1 = aldf(&pbuf[(t&1)*1024 + 2*tid + 1]);
        float s2 = p0 + p1;
        s2 += __shfl_xor(s2,1); s2 += __shfl_xor(s2,2); s2 += __shfl_xor(s2,4);
        s2 += __shfl_xor(s2,8); s2 += __shfl_xor(s2,16); s2 += __shfl_xor(s2,32);
        if ((tid & 63) == 0) wpart[tid >> 6] = s2;
        __syncthreads();
        if (tid == 0){
          float d = 0.f;
          #pragma unroll
          for (int kk = 0; kk < 8; ++kk) d += wpart[kk];
          invs = 1.f/d;
        }
        __syncthreads();
        float iv = invs;
        int q = tid >> 6, i8 = (tid & 63) >> 2, j = tid & 3;
        ((f16x2*)&ps8[i8*8 + q])[j] = (f16x2){ (f16)(p0*iv), (f16)(p1*iv) };
        if (tid < 16) Pout[(size_t)t*SRC + b*16 + tid] = pown[tid]*iv;
      }
      __syncthreads();
      // ---- S5: gates = gacc + V·p̂ + G for own 64 rows ----
      {
        const f16x8* wr = (const f16x8*)(Vt + (size_t)(b*64 + l8)*SRC + q8*128);
        float acc = 0.f;
        #pragma unroll
        for (int i = 0; i < 16; ++i){
          f16x8 wv = wr[i];
          f16x8 pv = ps8[i*8 + q8];
          const f16x2* wp = (const f16x2*)&wv;
          const f16x2* pp = (const f16x2*)&pv;
          acc = __builtin_amdgcn_fdot2(wp[0], pp[0], acc, false);
          acc = __builtin_amdgcn_fdot2(wp[1], pp[1], acc, false);
          acc = __builtin_amdgcn_fdot2(wp[2], pp[2], acc, false);
          acc = __builtin_amdgcn_fdot2(wp[3], pp[3], acc, false);
        }
        acc += __shfl_xor(acc,1); acc += __shfl_xor(acc,2); acc += __shfl_xor(acc,4);
        if (q8 == 0) g2[l8] = acc + gacc[l8] + (float)Gp[(size_t)t*4096 + b*64 + l8];
      }
      __syncthreads();
      // ---- S6: LSTM pointwise own 16 j-dims ----
      if (tid < 16){
        float gi = g2[tid], gf = g2[16+tid], gg = g2[32+tid], go = g2[48+tid];
        float cn = sigm(gf)*cst[tid] + sigm(gi)*tanh_f(gg);
        float hn = sigm(go)*tanh_f(cn);
        cst[tid] = cn;
        hnl[tid] = hn;
        Hh[(size_t)(t+1)*HID + b*16 + tid] = hn;        // history for workers
      }
      __syncthreads();
      if (tid < 8) hnl2[tid] = (f16x2){ (f16)hnl[2*tid], (f16)hnl[2*tid+1] };
      __syncthreads();
      // ---- S7: publish h + wahp partials, single counter bump ----
      if (tid < 8){
        union { f16x2 h; unsigned u; } cv;
        cv.h = hnl2[tid];
        astu(&hbuf[((t+1)&1)*512 + b*8 + tid], cv.u);
      } else if (tid >= 128 && tid < 256){
        int a = tid - 128;
        const f16x8* wt = (const f16x8*)(WahT + ((size_t)b*128 + a)*16);
        f16x8 w0 = wt[0], w1 = wt[1];
        const f16x2* wp0 = (const f16x2*)&w0;
        const f16x2* wp1 = (const f16x2*)&w1;
        float acc = 0.f;
        acc = __builtin_amdgcn_fdot2(wp0[0], hnl2[0], acc, false);
        acc = __builtin_amdgcn_fdot2(wp0[1], hnl2[1], acc, false);
        acc = __builtin_amdgcn_fdot2(wp0[2], hnl2[2], acc, false);
        acc = __builtin_amdgcn_fdot2(wp0[3], hnl2[3], acc, false);
        acc = __builtin_amdgcn_fdot2(wp1[0], hnl2[4], acc, false);
        acc = __builtin_amdgcn_fdot2(wp1[1], hnl2[5], acc, false);
        acc = __builtin_amdgcn_fdot2(wp1[2], hnl2[6], acc, false);
        acc = __builtin_amdgcn_fdot2(wp1[3], hnl2[7], acc, false);
        astf(&wahpb[((t+1)&1)*8192 + b*128 + a], acc);
      }
      __syncthreads();                                  // drain h+wahp stores
      if (tid == 0)
        __hip_atomic_fetch_add(&ctr[2], 1u, __ATOMIC_RELAXED, __HIP_MEMORY_SCOPE_AGENT);
    }
    if (tid < 16) Cc[b*16 + tid] = cst[tid];
  } else if (t0 > 0){
    // ================= logits workers: previous chunk's stripe =================
    // Rows from Hh (plain loads; previous LAUNCH wrote them -> visible).
    const int r = (b - NB)*512 + tid;                   // vocab row, 63*512=32256
    const bool act = (r < VOCAB);
    const float* wrow = act ? (Wout + (size_t)r*HID) : Wout;
    const float  bo   = act ? bout[r] : 0.f;
    #pragma unroll 1
    for (int sb = 0; sb < 4; ++sb){
      const int tb0 = (t0 - 64) + sb*16;                // logits t in [tb0, tb0+16)
      // load h rows tb0+1 .. tb0+16 (f32 -> f16 pairs in LDS)
      #pragma unroll 1
      for (int i = 0; i < 16; ++i){
        float2 hv = *reinterpret_cast<const float2*>(Hh + (size_t)(tb0 + 1 + i)*HID + 2*tid);
        hL[i][tid] = (f16x2){ (f16)hv.x, (f16)hv.y };
      }
      __syncthreads();
      float acc[16];
      #pragma unroll
      for (int tt = 0; tt < 16; ++tt) acc[tt] = 0.f;
      for (int k2 = 0; k2 < 512; ++k2){
        float2 w2 = *reinterpret_cast<const float2*>(wrow + 2*k2);
        #pragma unroll
        for (int tt = 0; tt < 16; ++tt){
          f16x2 h2 = hL[tt][k2];
          acc[tt] = fmaf(w2.x, (float)h2[0], acc[tt]);
          acc[tt] = fmaf(w2.y, (float)h2[1], acc[tt]);
        }
      }
      if (act){
        #pragma unroll
        for (int tt = 0; tt < 16; ++tt)
          Clog[(size_t)(tb0 + tt)*VOCAB + r] = acc[tt] + bo;
      }
      __syncthreads();
    }
  }
}

// ---- tail: logits rows m in [384,512) via bf16 MFMA (overwrites worker overlap) ----
__global__ __launch_bounds__(256) void k_gemm1(const float* __restrict__ A, const float* __restrict__ B,
                                               const float* __restrict__ bias, float* __restrict__ C){
  int bn = blockIdx.x;
  int tid = threadIdx.x;
  int wid = tid>>6, lane = tid&63;
  int wr = wid>>1, wc = wid&1;
  int rowf = lane&15, kg = lane>>4;
  const int m_base = 384 + wr*64;
  const int n_base = bn*128 + wc*64;
  const float* Ap = A + (size_t)(m_base + rowf)*HID + kg*8;
  const float* Bp = B + (size_t)(n_base + rowf)*HID + kg*8;
  f32x4 acc[4][4];
  #pragma unroll
  for (int i=0;i<4;i++)
    #pragma unroll
    for (int jv=0;jv<4;jv++) acc[i][jv] = (f32x4){0.f,0.f,0.f,0.f};
  for (int kk=0; kk<HID; kk+=32){
    bf16x8v av[4], bv[4];
    #pragma unroll
    for (int mt=0;mt<4;mt++) av[mt] = cvt8(Ap + (size_t)mt*16*HID + kk);
    #pragma unroll
    for (int nt=0;nt<4;nt++) bv[nt] = cvt8(Bp + (size_t)nt*16*HID + kk);
    #pragma unroll
    for (int mt=0;mt<4;mt++)
      #pragma unroll
      for (int nt=0;nt<4;nt++)
        acc[mt][nt] = __builtin_amdgcn_mfma_f32_16x16x32_bf16(av[mt], bv[nt], acc[mt][nt], 0,0,0);
  }
  #pragma unroll
  for (int mt=0;mt<4;mt++){
    #pragma unroll
    for (int nt=0;nt<4;nt++){
      int n = n_base + nt*16 + rowf;
      float bo = bias[n];
      #pragma unroll
      for (int i=0;i<4;i++){
        int m = m_base + mt*16 + kg*4 + i;
        C[(size_t)m*VOCAB + n] = acc[mt][nt][i] + bo;
      }
    }
  }
}

extern "C" void kernel_launch(void* const* d_in, const int* in_sizes, int n_in,
                              void* d_out, int out_size, void* d_ws, size_t ws_size,
                              hipStream_t stream){
  const float* enc    = (const float*)d_in[0];
  const float* h0     = (const float*)d_in[1];
  const float* c0     = (const float*)d_in[2];
  const int*   sos    = (const int*)d_in[3];
  const int*   tgt    = (const int*)d_in[4];
  const float* embt   = (const float*)d_in[5];
  const float* Wa_enc = (const float*)d_in[6];
  const float* Wa_h   = (const float*)d_in[7];
  const float* v_a    = (const float*)d_in[8];
  const float* W_ih   = (const float*)d_in[9];
  const float* W_hh   = (const float*)d_in[10];
  const float* b_ih   = (const float*)d_in[11];
  const float* b_hh   = (const float*)d_in[12];
  const float* W_out  = (const float*)d_in[13];
  const float* b_out  = (const float*)d_in[14];

  float* ws   = (float*)d_ws;
  unsigned* TP = (unsigned*)(ws + OFF_TP);
  f16*   Gp   = (f16*)(ws + OFF_G);
  float* Hh   = ws + OFF_HH;
  float* Cc   = ws + OFF_CC;
  float* wahpb= ws + OFF_WAHPB;
  float* pbuf = ws + OFF_PB;
  unsigned* hbuf = (unsigned*)(ws + OFF_HBUF);
  unsigned* ctr  = (unsigned*)(ws + OFF_CTR);
  f16*   WahT = (f16*)(ws + OFF_WAHT);
  f16*   Whh_h= (f16*)(ws + OFF_WHH);
  f16*   Vt   = (f16*)(ws + OFF_VT);

  float* out_logits = (float*)d_out;
  float* out_attn   = out_logits + (size_t)TGT*VOCAB;

  k_encTP   <<<64, 128, 0, stream>>>(enc, Wa_enc, v_a, TP);
  k_gbase   <<<dim3(16, 32), 256, 0, stream>>>(sos, tgt, embt, W_ih, b_ih, b_hh, Gp);
  k_cvt_whh <<<4096, 128, 0, stream>>>(W_hh, Whh_h);
  k_cvt_wahT<<<64, 128, 0, stream>>>(Wa_h, WahT);
  k_gemmV   <<<dim3(8, 32), 256, 0, stream>>>(W_ih, enc, Vt);
  k_prep0   <<<64, 128, 0, stream>>>(h0, c0, Wa_h, Hh, Cc, hbuf, wahpb, ctr);

  for (int t0 = 0; t0 < TGT; t0 += CHUNK){
    k_multi<<<NBW, NT, 0, stream>>>(t0, TP, WahT, Whh_h, Vt, Gp, v_a,
                                    Hh, Cc, wahpb, pbuf, hbuf, ctr, out_attn,
                                    W_out, b_out, out_logits);
  }

  k_gemm1<<<250, 256, 0, stream>>>(Hh + HID, W_out, b_out, out_logits);
}

// Round 16
// 3726.055 us; speedup vs baseline: 1.4372x; 1.4372x over previous
//
#include <hip/hip_runtime.h>
#include <hip/hip_bf16.h>

#define VOCAB 32000
#define EMBED 512
#define ENCD  512
#define HID   1024
#define ATTN  128
#define SRC   1024
#define TGT   512
#define NB    64          // recurrence blocks (proven sweet spot)
#define NT    512         // threads per block
#define CHUNK 64          // steps per launch (r13-proven)

typedef __hip_bfloat16 bf16;
typedef _Float16 f16;
typedef __attribute__((ext_vector_type(2))) _Float16 f16x2;
typedef __attribute__((ext_vector_type(8))) _Float16 f16x8;
typedef __attribute__((ext_vector_type(8))) short bf16x8v;
typedef __attribute__((ext_vector_type(4))) float f32x4;

// ---- workspace layout (float offsets) ----
#define OFF_TP    0           // u32 [1024][128] {T, v*T} f16 pairs
#define OFF_G     131072      // f16 [512][4096] gate bases, prow-permuted
#define OFF_HH    1179648     // f32 [513][1024] h history (for k_gemm)
#define OFF_CC    1704960     // f32 [1024] c state
#define OFF_WAHPB 1705984     // f32 [2][64][128] wahp partials dbuf (atomic)
#define OFF_PB    1722368     // f32 [2][1024] unnorm p dbuf        (atomic)
#define OFF_HBUF  1724416     // u32 [2][512] h packed f16x2 dbuf   (atomic)
#define OFF_CTR   1725440     // u32 [3] counters (+pad)            (atomic)
#define OFF_WAHT  1725504     // f16 [64][128][16] Wa_h block-sliced
#define OFF_WHH   1791040     // f16 [4096][1024] W_hh, prow-permuted
#define OFF_VT    3888192     // f16 [4096][1024] V[prow][s]
#define OFF_WOUTB 5985344     // bf16 [32000][1024] W_out (optional, ws-size-gated)
#define WS_NEED_BF16 ((size_t)(OFF_WOUTB + (VOCAB*HID/2))*4)   // ~89.5 MB

__device__ __forceinline__ float sigm(float x){ return 1.f/(1.f+__expf(-x)); }
__device__ __forceinline__ float tanh_f(float x){
  float ax = fabsf(x);
  float e = __expf(-2.f*ax);
  float r = (1.f - e) / (1.f + e);
  return copysignf(r, x);
}
__device__ __forceinline__ short f2bs(float x){
  union { bf16 h; short s; } u; u.h = __float2bfloat16(x); return u.s;
}
__device__ __forceinline__ bf16x8v cvt8(const float* p){
  float4 a = *reinterpret_cast<const float4*>(p);
  float4 b = *reinterpret_cast<const float4*>(p+4);
  bf16x8v r;
  r[0]=f2bs(a.x); r[1]=f2bs(a.y); r[2]=f2bs(a.z); r[3]=f2bs(a.w);
  r[4]=f2bs(b.x); r[5]=f2bs(b.y); r[6]=f2bs(b.z); r[7]=f2bs(b.w);
  return r;
}
__device__ __forceinline__ float aldf(const float* p){
  return __hip_atomic_load(p, __ATOMIC_RELAXED, __HIP_MEMORY_SCOPE_AGENT);
}
__device__ __forceinline__ void astf(float* p, float v){
  __hip_atomic_store(p, v, __ATOMIC_RELAXED, __HIP_MEMORY_SCOPE_AGENT);
}
__device__ __forceinline__ unsigned aldu(const unsigned* p){
  return __hip_atomic_load(p, __ATOMIC_RELAXED, __HIP_MEMORY_SCOPE_AGENT);
}
__device__ __forceinline__ void astu(unsigned* p, unsigned v){
  __hip_atomic_store(p, v, __ATOMIC_RELAXED, __HIP_MEMORY_SCOPE_AGENT);
}

// ---- one-time: TP[s][a] = {T, v_a*T}, T = clamp(tanh(enc_proj)) (grid 64x128) ----
__global__ void k_encTP(const float* __restrict__ enc, const float* __restrict__ Wa_enc,
                        const float* __restrict__ v_a, unsigned* __restrict__ TP){
  __shared__ float eL[16][ENCD];
  int s0 = blockIdx.x*16, tid = threadIdx.x;
  #pragma unroll
  for (int i=0;i<16;i++){
    int li = tid + i*128;
    int t = li>>7, k4 = li&127;
    *reinterpret_cast<float4*>(&eL[t][k4*4]) =
      *reinterpret_cast<const float4*>(enc + (size_t)(s0+t)*ENCD + k4*4);
  }
  __syncthreads();
  const float* w = Wa_enc + (size_t)tid*ENCD;
  float va = v_a[tid];
  float acc[16];
  #pragma unroll
  for (int t=0;t<16;t++) acc[t]=0.f;
  for (int k4=0;k4<128;k4++){
    float4 wv = *reinterpret_cast<const float4*>(w + k4*4);
    #pragma unroll
    for (int t=0;t<16;t++){
      float4 e4 = *reinterpret_cast<const float4*>(&eL[t][k4*4]);
      acc[t] += wv.x*e4.x + wv.y*e4.y + wv.z*e4.z + wv.w*e4.w;
    }
  }
  #pragma unroll
  for (int t=0;t<16;t++){
    float th = tanh_f(acc[t]);
    th = fminf(0.9995f, fmaxf(-0.9995f, th));
    union { f16x2 h; unsigned u; } cv;
    cv.h = (f16x2){ (f16)th, (f16)(va*th) };
    TP[(size_t)(s0+t)*ATTN + tid] = cv.u;
  }
}

// ---- one-time: Gp[t][prow] f16, prow = (j>>4)*64 + g*16 + (j&15) ----
__global__ void k_gbase(const int* __restrict__ sos, const int* __restrict__ tgt,
                        const float* __restrict__ embt, const float* __restrict__ W_ih,
                        const float* __restrict__ b_ih, const float* __restrict__ b_hh,
                        f16* __restrict__ Gp){
  __shared__ float eL[16][EMBED];
  int tid = threadIdx.x;
  int t0 = blockIdx.y*16;
  #pragma unroll
  for (int i=0;i<8;i++){
    int li = tid + i*256;
    int t = li>>7, k4 = li&127;
    int tg = t0 + t;
    int tok = (tg==0) ? sos[0] : tgt[tg-1];
    *reinterpret_cast<float4*>(&eL[t][k4*4]) =
      *reinterpret_cast<const float4*>(embt + (size_t)tok*EMBED + k4*4);
  }
  __syncthreads();
  int r = blockIdx.x*256 + tid;
  int g = r>>10, j = r&1023;
  int prow = (j>>4)*64 + g*16 + (j&15);
  const float* w = W_ih + (size_t)r*(EMBED+ENCD);
  float base = b_ih[r] + b_hh[r];
  float acc[16];
  #pragma unroll
  for (int t=0;t<16;t++) acc[t]=0.f;
  for (int k4=0;k4<128;k4++){
    float4 wv = *reinterpret_cast<const float4*>(w + k4*4);
    #pragma unroll
    for (int t=0;t<16;t++){
      float4 e4 = *reinterpret_cast<const float4*>(&eL[t][k4*4]);
      acc[t] += wv.x*e4.x + wv.y*e4.y + wv.z*e4.z + wv.w*e4.w;
    }
  }
  #pragma unroll
  for (int t=0;t<16;t++) Gp[(size_t)(t0+t)*4096 + prow] = (f16)(acc[t] + base);
}

// ---- one-time: W_hh -> f16 permuted rows ----
__global__ void k_cvt_whh(const float* __restrict__ W, f16* __restrict__ out){
  int r = blockIdx.x;
  int g = r >> 10, j = r & 1023;
  int prow = (j>>4)*64 + g*16 + (j&15);
  int k0 = threadIdx.x*8;
  float4 a = *reinterpret_cast<const float4*>(W + (size_t)r*HID + k0);
  float4 c = *reinterpret_cast<const float4*>(W + (size_t)r*HID + k0 + 4);
  f16x8 v = { (f16)a.x,(f16)a.y,(f16)a.z,(f16)a.w,(f16)c.x,(f16)c.y,(f16)c.z,(f16)c.w };
  *reinterpret_cast<f16x8*>(out + (size_t)prow*HID + k0) = v;
}
// ---- one-time: WahT[b][a][j] = Wa_h[a][b*16+j] f16 (grid 64 x 128) ----
__global__ void k_cvt_wahT(const float* __restrict__ W, f16* __restrict__ out){
  int b = blockIdx.x, a = threadIdx.x;
  const float* src = W + (size_t)a*HID + b*16;
  float4 v0 = *reinterpret_cast<const float4*>(src);
  float4 v1 = *reinterpret_cast<const float4*>(src+4);
  float4 v2 = *reinterpret_cast<const float4*>(src+8);
  float4 v3 = *reinterpret_cast<const float4*>(src+12);
  f16* dst = out + ((size_t)b*128 + a)*16;
  f16x8 w0 = { (f16)v0.x,(f16)v0.y,(f16)v0.z,(f16)v0.w,(f16)v1.x,(f16)v1.y,(f16)v1.z,(f16)v1.w };
  f16x8 w1 = { (f16)v2.x,(f16)v2.y,(f16)v2.z,(f16)v2.w,(f16)v3.x,(f16)v3.y,(f16)v3.z,(f16)v3.w };
  *reinterpret_cast<f16x8*>(dst)   = w0;
  *reinterpret_cast<f16x8*>(dst+8) = w1;
}
// ---- one-time: W_out -> bf16 (grid 32000 x 128) ----
__global__ void k_cvt_wout(const float* __restrict__ W, bf16* __restrict__ out){
  int r = blockIdx.x;
  int k0 = threadIdx.x*8;
  bf16x8v v = cvt8(W + (size_t)r*HID + k0);
  *reinterpret_cast<bf16x8v*>((short*)out + (size_t)r*HID + k0) = v;
}

// ---- one-time: Vt[prow][s] = Wihc[prow]·enc[s] via bf16 MFMA (grid 8 x 32) ----
__global__ __launch_bounds__(256) void k_gemmV(const float* __restrict__ W_ih,
                                               const float* __restrict__ enc,
                                               f16* __restrict__ Vt){
  int bn = blockIdx.x, bm = blockIdx.y;
  int tid = threadIdx.x;
  int wid = tid>>6, lane = tid&63;
  int wr = wid>>1, wc = wid&1;
  int rowf = lane&15, kg = lane>>4;
  const int m_base = bm*128 + wr*64;
  const int n_base = bn*128 + wc*64;
  const float* Ap[4];
  #pragma unroll
  for (int mt=0;mt<4;mt++){
    int prow = m_base + mt*16 + rowf;
    int bb = prow>>6, g = (prow>>4)&3, jl = prow&15;   // inverse perm
    int r = g*HID + bb*16 + jl;
    Ap[mt] = W_ih + (size_t)r*(EMBED+ENCD) + EMBED + kg*8;
  }
  const float* Bp = enc + (size_t)(n_base + rowf)*ENCD + kg*8;
  f32x4 acc[4][4];
  #pragma unroll
  for (int i=0;i<4;i++)
    #pragma unroll
    for (int jv=0;jv<4;jv++) acc[i][jv] = (f32x4){0.f,0.f,0.f,0.f};
  for (int kk=0; kk<ENCD; kk+=32){
    bf16x8v av[4], bv[4];
    #pragma unroll
    for (int mt=0;mt<4;mt++) av[mt] = cvt8(Ap[mt] + kk);
    #pragma unroll
    for (int nt=0;nt<4;nt++) bv[nt] = cvt8(Bp + (size_t)nt*16*ENCD + kk);
    #pragma unroll
    for (int mt=0;mt<4;mt++)
      #pragma unroll
      for (int nt=0;nt<4;nt++)
        acc[mt][nt] = __builtin_amdgcn_mfma_f32_16x16x32_bf16(av[mt], bv[nt], acc[mt][nt], 0,0,0);
  }
  #pragma unroll
  for (int mt=0;mt<4;mt++){
    #pragma unroll
    for (int nt=0;nt<4;nt++){
      int n = n_base + nt*16 + rowf;
      #pragma unroll
      for (int i=0;i<4;i++){
        int m = m_base + mt*16 + kg*4 + i;
        Vt[(size_t)m*SRC + n] = (f16)acc[mt][nt][i];
      }
    }
  }
}

// ---- one-time: Hh[0]=h0, Cc=c0, hbuf[0], wahp[0], ctr=0 (grid 64 x 128) ----
__global__ void k_prep0(const float* __restrict__ h0, const float* __restrict__ c0,
                        const float* __restrict__ Wa_h,
                        float* __restrict__ Hh, float* __restrict__ Cc,
                        unsigned* __restrict__ hbuf, float* __restrict__ wahpb,
                        unsigned* __restrict__ ctr){
  int b = blockIdx.x, tid = threadIdx.x;
  if (b < 8){ Hh[b*128+tid] = h0[b*128+tid]; Cc[b*128+tid] = c0[b*128+tid]; }
  if (b < 4){
    int i = b*128 + tid;
    union { f16x2 h; unsigned u; } cv;
    cv.h = (f16x2){ (f16)h0[2*i], (f16)h0[2*i+1] };
    hbuf[i] = cv.u;
  }
  if (b == 0 && tid < 3) ctr[tid] = 0u;
  __shared__ float hl[16];
  if (tid < 16) hl[tid] = h0[b*16 + tid];
  __syncthreads();
  const float* wr = Wa_h + (size_t)tid*HID + b*16;
  float acc = 0.f;
  #pragma unroll
  for (int i4=0;i4<4;i4++){
    float4 w4 = *reinterpret_cast<const float4*>(wr + i4*4);
    acc += w4.x*hl[i4*4] + w4.y*hl[i4*4+1] + w4.z*hl[i4*4+2] + w4.w*hl[i4*4+3];
  }
  wahpb[b*128 + tid] = acc;   // parity 0
}

// ---- CHUNK steps per launch: 64 blocks x 512 thr; 2 counter syncs/step (r13) ----
__global__ __launch_bounds__(NT) void k_multi(int t0,
    const unsigned* __restrict__ TP, const f16* __restrict__ WahT,
    const f16* __restrict__ Whh_h, const f16* __restrict__ Vt,
    const f16* __restrict__ Gp, const float* __restrict__ v_a,
    float* __restrict__ Hh, float* __restrict__ Cc,
    float* __restrict__ wahpb, float* __restrict__ pbuf,
    unsigned* __restrict__ hbuf, unsigned* __restrict__ ctr,
    float* __restrict__ Pout)
{
  const int b = blockIdx.x, tid = threadIdx.x;
  __shared__ f16x8 hs8[128];       // h_t packed, swizzled [(c&15)*8+(c>>4)]
  __shared__ f16x8 ps8[128];       // normalized p packed, same swizzle
  __shared__ float2 vwp[128];      // {tanh(wah), v*tanh(wah)}
  __shared__ float vas[128];
  __shared__ float gacc[64];
  __shared__ float g2[64];
  __shared__ float pown[16];
  __shared__ float hnl[16];
  __shared__ f16x2 hnl2[8];
  __shared__ float wpart[8];
  __shared__ float invs;
  __shared__ float cst[16];

  const int l8 = tid >> 3, q8 = tid & 7;   // matvec: 64 rows x 8 lanes

  if (tid < 16)  cst[tid] = Cc[b*16 + tid];
  if (tid < 128) vas[tid] = v_a[tid];

  for (int k = 0; k < CHUNK; ++k){
    const int t = t0 + k;
    const unsigned base = 64u*(unsigned)t;
    // ---- S0: wait h+wahp ready (single sync); load h; reduce wahp ----
    if (tid == 0){
      while (aldu(&ctr[2]) < base) __builtin_amdgcn_s_sleep(1);
    }
    __syncthreads();
    if (tid < 128){
      const unsigned* hp = hbuf + (t&1)*512 + tid*4;
      union { unsigned u[4]; f16x8 v; } cv;
      cv.u[0]=aldu(hp); cv.u[1]=aldu(hp+1); cv.u[2]=aldu(hp+2); cv.u[3]=aldu(hp+3);
      hs8[(tid&15)*8 + (tid>>4)] = cv.v;
    }
    {
      int a = tid >> 2, lane4 = tid & 3;
      const float* wp = wahpb + (t&1)*8192 + lane4*128 + a;
      float acc = 0.f;
      #pragma unroll
      for (int m = 0; m < 16; ++m) acc += aldf(wp + m*512);
      acc += __shfl_xor(acc,1); acc += __shfl_xor(acc,2);
      if (lane4 == 0){
        float tw = tanh_f(acc);
        vwp[a] = make_float2(tw, vas[a]*tw);
      }
    }
    __syncthreads();
    // ---- S1: scores for own 16 s-rows; publish p ----
    {
      int row = tid >> 5, l5 = tid & 31;
      const f16x8* tp8 = (const f16x8*)((const f16*)TP + ((size_t)(b*16+row)*ATTN + l5*4)*2);
      f16x8 tv = tp8[0];
      float sc = 0.f;
      #pragma unroll
      for (int u = 0; u < 4; ++u){
        float T  = (float)tv[2*u];
        float vT = (float)tv[2*u+1];
        float2 vw = vwp[l5*4 + u];
        float num = vT + vw.y;
        float den = fmaf(T, vw.x, 1.f);
        sc = fmaf(num, __builtin_amdgcn_rcpf(den), sc);
      }
      sc += __shfl_xor(sc,1); sc += __shfl_xor(sc,2); sc += __shfl_xor(sc,4);
      sc += __shfl_xor(sc,8); sc += __shfl_xor(sc,16);
      if (l5 == 0){
        float pv = __expf(sc);
        pown[row] = pv;
        astf(&pbuf[(t&1)*1024 + b*16 + row], pv);
      }
    }
    __syncthreads();                                  // drain p stores
    if (tid == 0)
      __hip_atomic_fetch_add(&ctr[1], 1u, __ATOMIC_RELAXED, __HIP_MEMORY_SCOPE_AGENT);
    // ---- S2: full gacc = Whh·h (hides p round-trip) ----
    {
      const f16x8* wr = (const f16x8*)(Whh_h + (size_t)(b*64 + l8)*HID + q8*128);
      float ga = 0.f;
      #pragma unroll
      for (int i = 0; i < 16; ++i){
        f16x8 wv = wr[i];
        f16x8 hv = hs8[i*8 + q8];
        const f16x2* wp = (const f16x2*)&wv;
        const f16x2* hp = (const f16x2*)&hv;
        ga = __builtin_amdgcn_fdot2(wp[0], hp[0], ga, false);
        ga = __builtin_amdgcn_fdot2(wp[1], hp[1], ga, false);
        ga = __builtin_amdgcn_fdot2(wp[2], hp[2], ga, false);
        ga = __builtin_amdgcn_fdot2(wp[3], hp[3], ga, false);
      }
      ga += __shfl_xor(ga,1); ga += __shfl_xor(ga,2); ga += __shfl_xor(ga,4);
      if (q8 == 0) gacc[l8] = ga;
    }
    // ---- S3: wait p; normalize + pack ----
    if (tid == 0){
      while (aldu(&ctr[1]) < base + 64u) __builtin_amdgcn_s_sleep(1);
    }
    __syncthreads();
    {
      float p0 = aldf(&pbuf[(t&1)*1024 + 2*tid]);
      float p1 = aldf(&pbuf[(t&1)*1024 + 2*tid + 1]);
      float s2 = p0 + p1;
      s2 += __shfl_xor(s2,1); s2 += __shfl_xor(s2,2); s2 += __shfl_xor(s2,4);
      s2 += __shfl_xor(s2,8); s2 += __shfl_xor(s2,16); s2 += __shfl_xor(s2,32);
      if ((tid & 63) == 0) wpart[tid >> 6] = s2;
      __syncthreads();
      if (tid == 0){
        float d = 0.f;
        #pragma unroll
        for (int kk = 0; kk < 8; ++kk) d += wpart[kk];
        invs = 1.f/d;
      }
      __syncthreads();
      float iv = invs;
      int q = tid >> 6, i8 = (tid & 63) >> 2, j = tid & 3;
      ((f16x2*)&ps8[i8*8 + q])[j] = (f16x2){ (f16)(p0*iv), (f16)(p1*iv) };
      if (tid < 16) Pout[(size_t)t*SRC + b*16 + tid] = pown[tid]*iv;
    }
    __syncthreads();
    // ---- S5: gates = gacc + V·p̂ + G for own 64 rows ----
    {
      const f16x8* wr = (const f16x8*)(Vt + (size_t)(b*64 + l8)*SRC + q8*128);
      float acc = 0.f;
      #pragma unroll
      for (int i = 0; i < 16; ++i){
        f16x8 wv = wr[i];
        f16x8 pv = ps8[i*8 + q8];
        const f16x2* wp = (const f16x2*)&wv;
        const f16x2* pp = (const f16x2*)&pv;
        acc = __builtin_amdgcn_fdot2(wp[0], pp[0], acc, false);
        acc = __builtin_amdgcn_fdot2(wp[1], pp[1], acc, false);
        acc = __builtin_amdgcn_fdot2(wp[2], pp[2], acc, false);
        acc = __builtin_amdgcn_fdot2(wp[3], pp[3], acc, false);
      }
      acc += __shfl_xor(acc,1); acc += __shfl_xor(acc,2); acc += __shfl_xor(acc,4);
      if (q8 == 0) g2[l8] = acc + gacc[l8] + (float)Gp[(size_t)t*4096 + b*64 + l8];
    }
    __syncthreads();
    // ---- S6: LSTM pointwise own 16 j-dims ----
    if (tid < 16){
      float gi = g2[tid], gf = g2[16+tid], gg = g2[32+tid], go = g2[48+tid];
      float cn = sigm(gf)*cst[tid] + sigm(gi)*tanh_f(gg);
      float hn = sigm(go)*tanh_f(cn);
      cst[tid] = cn;
      hnl[tid] = hn;
      Hh[(size_t)(t+1)*HID + b*16 + tid] = hn;        // history for k_gemm
    }
    __syncthreads();
    if (tid < 8) hnl2[tid] = (f16x2){ (f16)hnl[2*tid], (f16)hnl[2*tid+1] };
    __syncthreads();
    // ---- S7: publish h + wahp partials, single counter bump ----
    if (tid < 8){
      union { f16x2 h; unsigned u; } cv;
      cv.h = hnl2[tid];
      astu(&hbuf[((t+1)&1)*512 + b*8 + tid], cv.u);
    } else if (tid >= 128 && tid < 256){
      int a = tid - 128;
      const f16x8* wt = (const f16x8*)(WahT + ((size_t)b*128 + a)*16);
      f16x8 w0 = wt[0], w1 = wt[1];
      const f16x2* wp0 = (const f16x2*)&w0;
      const f16x2* wp1 = (const f16x2*)&w1;
      float acc = 0.f;
      acc = __builtin_amdgcn_fdot2(wp0[0], hnl2[0], acc, false);
      acc = __builtin_amdgcn_fdot2(wp0[1], hnl2[1], acc, false);
      acc = __builtin_amdgcn_fdot2(wp0[2], hnl2[2], acc, false);
      acc = __builtin_amdgcn_fdot2(wp0[3], hnl2[3], acc, false);
      acc = __builtin_amdgcn_fdot2(wp1[0], hnl2[4], acc, false);
      acc = __builtin_amdgcn_fdot2(wp1[1], hnl2[5], acc, false);
      acc = __builtin_amdgcn_fdot2(wp1[2], hnl2[6], acc, false);
      acc = __builtin_amdgcn_fdot2(wp1[3], hnl2[7], acc, false);
      astf(&wahpb[((t+1)&1)*8192 + b*128 + a], acc);
    }
    __syncthreads();                                  // drain h+wahp stores
    if (tid == 0)
      __hip_atomic_fetch_add(&ctr[2], 1u, __ATOMIC_RELAXED, __HIP_MEMORY_SCOPE_AGENT);
  }
  if (tid < 16) Cc[b*16 + tid] = cst[tid];
}

// ---- epilogue: logits, B pre-converted bf16; XCD-swizzled 1000-block grid ----
__global__ __launch_bounds__(256) void k_gemm_b(const float* __restrict__ A, const bf16* __restrict__ B,
                                                const float* __restrict__ bias, float* __restrict__ C){
  int bid = blockIdx.x;
  int tile = (bid & 7)*125 + (bid >> 3);   // XCD-contiguous tile ranges
  int bm = tile & 3, bn = tile >> 2;
  int tid = threadIdx.x;
  int wid = tid>>6, lane = tid&63;
  int wr = wid>>1, wc = wid&1;
  int rowf = lane&15, kg = lane>>4;
  const int m_base = bm*128 + wr*64;
  const int n_base = bn*128 + wc*64;
  const float* Ap = A + (size_t)(m_base + rowf)*HID + kg*8;
  const short* Bp = (const short*)B + (size_t)(n_base + rowf)*HID + kg*8;
  f32x4 acc[4][4];
  #pragma unroll
  for (int i=0;i<4;i++)
    #pragma unroll
    for (int jv=0;jv<4;jv++) acc[i][jv] = (f32x4){0.f,0.f,0.f,0.f};
  for (int kk=0; kk<HID; kk+=32){
    bf16x8v av[4], bv[4];
    #pragma unroll
    for (int mt=0;mt<4;mt++) av[mt] = cvt8(Ap + (size_t)mt*16*HID + kk);
    #pragma unroll
    for (int nt=0;nt<4;nt++) bv[nt] = *reinterpret_cast<const bf16x8v*>(Bp + (size_t)nt*16*HID + kk);
    #pragma unroll
    for (int mt=0;mt<4;mt++)
      #pragma unroll
      for (int nt=0;nt<4;nt++)
        acc[mt][nt] = __builtin_amdgcn_mfma_f32_16x16x32_bf16(av[mt], bv[nt], acc[mt][nt], 0,0,0);
  }
  #pragma unroll
  for (int mt=0;mt<4;mt++){
    #pragma unroll
    for (int nt=0;nt<4;nt++){
      int n = n_base + nt*16 + rowf;
      float bo = bias[n];
      #pragma unroll
      for (int i=0;i<4;i++){
        int m = m_base + mt*16 + kg*4 + i;
        C[(size_t)m*VOCAB + n] = acc[mt][nt][i] + bo;
      }
    }
  }
}

// ---- fallback epilogue (f32 B, cvt on the fly) — used if ws too small ----
__global__ __launch_bounds__(256) void k_gemm(const float* __restrict__ A, const float* __restrict__ B,
                                              const float* __restrict__ bias, float* __restrict__ C){
  int bid = blockIdx.x;
  int tile = (bid & 7)*125 + (bid >> 3);
  int bm = tile & 3, bn = tile >> 2;
  int tid = threadIdx.x;
  int wid = tid>>6, lane = tid&63;
  int wr = wid>>1, wc = wid&1;
  int rowf = lane&15, kg = lane>>4;
  const int m_base = bm*128 + wr*64;
  const int n_base = bn*128 + wc*64;
  const float* Ap = A + (size_t)(m_base + rowf)*HID + kg*8;
  const float* Bp = B + (size_t)(n_base + rowf)*HID + kg*8;
  f32x4 acc[4][4];
  #pragma unroll
  for (int i=0;i<4;i++)
    #pragma unroll
    for (int jv=0;jv<4;jv++) acc[i][jv] = (f32x4){0.f,0.f,0.f,0.f};
  for (int kk=0; kk<HID; kk+=32){
    bf16x8v av[4], bv[4];
    #pragma unroll
    for (int mt=0;mt<4;mt++) av[mt] = cvt8(Ap + (size_t)mt*16*HID + kk);
    #pragma unroll
    for (int nt=0;nt<4;nt++) bv[nt] = cvt8(Bp + (size_t)nt*16*HID + kk);
    #pragma unroll
    for (int mt=0;mt<4;mt++)
      #pragma unroll
      for (int nt=0;nt<4;nt++)
        acc[mt][nt] = __builtin_amdgcn_mfma_f32_16x16x32_bf16(av[mt], bv[nt], acc[mt][nt], 0,0,0);
  }
  #pragma unroll
  for (int mt=0;mt<4;mt++){
    #pragma unroll
    for (int nt=0;nt<4;nt++){
      int n = n_base + nt*16 + rowf;
      float bo = bias[n];
      #pragma unroll
      for (int i=0;i<4;i++){
        int m = m_base + mt*16 + kg*4 + i;
        C[(size_t)m*VOCAB + n] = acc[mt][nt][i] + bo;
      }
    }
  }
}

extern "C" void kernel_launch(void* const* d_in, const int* in_sizes, int n_in,
                              void* d_out, int out_size, void* d_ws, size_t ws_size,
                              hipStream_t stream){
  const float* enc    = (const float*)d_in[0];
  const float* h0     = (const float*)d_in[1];
  const float* c0     = (const float*)d_in[2];
  const int*   sos    = (const int*)d_in[3];
  const int*   tgt    = (const int*)d_in[4];
  const float* embt   = (const float*)d_in[5];
  const float* Wa_enc = (const float*)d_in[6];
  const float* Wa_h   = (const float*)d_in[7];
  const float* v_a    = (const float*)d_in[8];
  const float* W_ih   = (const float*)d_in[9];
  const float* W_hh   = (const float*)d_in[10];
  const float* b_ih   = (const float*)d_in[11];
  const float* b_hh   = (const float*)d_in[12];
  const float* W_out  = (const float*)d_in[13];
  const float* b_out  = (const float*)d_in[14];

  float* ws   = (float*)d_ws;
  unsigned* TP = (unsigned*)(ws + OFF_TP);
  f16*   Gp   = (f16*)(ws + OFF_G);
  float* Hh   = ws + OFF_HH;
  float* Cc   = ws + OFF_CC;
  float* wahpb= ws + OFF_WAHPB;
  float* pbuf = ws + OFF_PB;
  unsigned* hbuf = (unsigned*)(ws + OFF_HBUF);
  unsigned* ctr  = (unsigned*)(ws + OFF_CTR);
  f16*   WahT = (f16*)(ws + OFF_WAHT);
  f16*   Whh_h= (f16*)(ws + OFF_WHH);
  f16*   Vt   = (f16*)(ws + OFF_VT);
  bf16*  WoutB= (bf16*)(ws + OFF_WOUTB);

  const bool use_b16 = (ws_size >= WS_NEED_BF16);

  float* out_logits = (float*)d_out;
  float* out_attn   = out_logits + (size_t)TGT*VOCAB;

  k_encTP   <<<64, 128, 0, stream>>>(enc, Wa_enc, v_a, TP);
  k_gbase   <<<dim3(16, 32), 256, 0, stream>>>(sos, tgt, embt, W_ih, b_ih, b_hh, Gp);
  k_cvt_whh <<<4096, 128, 0, stream>>>(W_hh, Whh_h);
  k_cvt_wahT<<<64, 128, 0, stream>>>(Wa_h, WahT);
  k_gemmV   <<<dim3(8, 32), 256, 0, stream>>>(W_ih, enc, Vt);
  if (use_b16)
    k_cvt_wout<<<VOCAB, 128, 0, stream>>>(W_out, WoutB);
  k_prep0   <<<64, 128, 0, stream>>>(h0, c0, Wa_h, Hh, Cc, hbuf, wahpb, ctr);

  for (int t0 = 0; t0 < TGT; t0 += CHUNK){
    k_multi<<<NB, NT, 0, stream>>>(t0, TP, WahT, Whh_h, Vt, Gp, v_a,
                                   Hh, Cc, wahpb, pbuf, hbuf, ctr, out_attn);
  }

  if (use_b16)
    k_gemm_b<<<1000, 256, 0, stream>>>(Hh + HID, WoutB, b_out, out_logits);
  else
    k_gemm  <<<1000, 256, 0, stream>>>(Hh + HID, W_out, b_out, out_logits);
}